// Round 9
// baseline (255.093 us; speedup 1.0000x reference)
//
#include <hip/hip_runtime.h>
#include <hip/hip_bf16.h>

#define SEQ 4096
#define BATCH 2
#define HEADS 16
#define DHEAD 64
#define HID 1024

typedef unsigned short ushort_t;
typedef unsigned int uint_t;
typedef __attribute__((ext_vector_type(8))) short short8;
typedef __attribute__((ext_vector_type(4))) float f32x4;
typedef __attribute__((ext_vector_type(16))) float f32x16;
typedef __attribute__((ext_vector_type(4))) uint_t u32x4;

__device__ __forceinline__ float exp2_fast(float x) {
  return __builtin_amdgcn_exp2f(x);  // v_exp_f32 computes 2^x natively
}

__device__ __forceinline__ float max3f(float a, float b, float c) {
  float r;
  asm("v_max3_f32 %0, %1, %2, %3" : "=v"(r) : "v"(a), "v"(b), "v"(c));
  return r;
}

__device__ __forceinline__ ushort_t f2b(float f) {
  unsigned u = __builtin_bit_cast(unsigned, f);
  unsigned r = 0x7fffu + ((u >> 16) & 1u);
  return (ushort_t)((u + r) >> 16);
}

__device__ __forceinline__ uint_t cvt_pk_bf16(float lo, float hi) {
  uint_t r;
  asm("v_cvt_pk_bf16_f32 %0, %1, %2" : "=v"(r) : "v"(lo), "v"(hi));
  return r;
}

// swap a's hi-32-lane half with b's lo-32-lane half (CDNA4 cross-lane, VALU pipe)
__device__ __forceinline__ void permlane_swap(uint_t& a, uint_t& b) {
  asm("v_permlane32_swap_b32 %0, %1" : "+v"(a), "+v"(b));
}

__device__ __forceinline__ void gload16(const void* g, void* l) {
  __builtin_amdgcn_global_load_lds((const __attribute__((address_space(1))) void*)g,
                                   (__attribute__((address_space(3))) void*)l, 16, 0, 0);
}

__device__ __forceinline__ f32x4 mfma_bf16(short8 a, short8 b, f32x4 c) {
  return __builtin_amdgcn_mfma_f32_16x16x32_bf16(a, b, c, 0, 0, 0);
}

__device__ __forceinline__ f32x16 mfma32_bf16(short8 a, short8 b, f32x16 c) {
  return __builtin_amdgcn_mfma_f32_32x32x16_bf16(a, b, c, 0, 0, 0);
}

// ---------------- fp32 -> bf16 elementwise (vectorized) ----------------
__global__ void cvt_kernel(const float* __restrict__ in, ushort_t* __restrict__ out, int n4) {
  int i = blockIdx.x * blockDim.x + threadIdx.x;
  if (i >= n4) return;
  float4 v = reinterpret_cast<const float4*>(in)[i];
  ushort4 o;
  o.x = f2b(v.x); o.y = f2b(v.y); o.z = f2b(v.z); o.w = f2b(v.w);
  reinterpret_cast<ushort4*>(out)[i] = o;
}

// ---------------- transpose + convert: in[rows][cols] f32 -> out[cols][rows] bf16 ----------------
__global__ void transpose_cvt_kernel(const float* __restrict__ in, ushort_t* __restrict__ out,
                                     int rows, int cols) {
  __shared__ float tile[32][33];
  int tx = threadIdx.x & 31, ty = threadIdx.x >> 5;
  int r0 = blockIdx.y * 32, c0 = blockIdx.x * 32;
#pragma unroll
  for (int i = 0; i < 32; i += 8)
    tile[ty + i][tx] = in[(size_t)(r0 + ty + i) * cols + c0 + tx];
  __syncthreads();
#pragma unroll
  for (int i = 0; i < 32; i += 8)
    out[(size_t)(c0 + ty + i) * rows + r0 + tx] = f2b(tile[tx][ty + i]);
}

// ---------------- bf16 GEMM: C = A[M][K] * BT[N][K]^T ----------------
// MODE 0: scatter-write q(*0.125*log2e)/k/vT bf16.  MODE 1: write fp32 C.
template <int MODE>
__global__ __launch_bounds__(256, 2)
void gemm_kernel(const ushort_t* __restrict__ A, const ushort_t* __restrict__ BT,
                 int M, int N, int K,
                 ushort_t* __restrict__ qg, ushort_t* __restrict__ kg,
                 ushort_t* __restrict__ vTg, float* __restrict__ outf) {
  __shared__ ushort_t lA[128 * 64];
  __shared__ ushort_t lB[128 * 64];
  int tid = threadIdx.x;
  int lane = tid & 63, w = tid >> 6;
  int m0 = blockIdx.x * 128, n0 = blockIdx.y * 128;
  int wr = (w >> 1) * 64, wc = (w & 1) * 64;
  int lr = lane & 15, lg = lane >> 4;

  const f32x4 z4 = {0.f, 0.f, 0.f, 0.f};
  f32x4 acc[4][4];
#pragma unroll
  for (int m = 0; m < 4; ++m)
#pragma unroll
    for (int n = 0; n < 4; ++n) acc[m][n] = z4;

  int ktiles = K >> 6;
  for (int kt = 0; kt < ktiles; ++kt) {
    int k0 = kt << 6;
#pragma unroll
    for (int i = 0; i < 4; ++i) {
      int c = i * 256 + tid;
      int row = c >> 3, cc = c & 7;
      gload16(A + (size_t)(m0 + row) * K + k0 + (cc ^ (row & 7)) * 8, lA + c * 8);
    }
#pragma unroll
    for (int i = 0; i < 4; ++i) {
      int c = i * 256 + tid;
      int row = c >> 3, cc = c & 7;
      gload16(BT + (size_t)(n0 + row) * K + k0 + (cc ^ (row & 7)) * 8, lB + c * 8);
    }
    __syncthreads();
#pragma unroll
    for (int kk = 0; kk < 2; ++kk) {
      short8 a[4], b[4];
#pragma unroll
      for (int m = 0; m < 4; ++m) {
        int row = wr + m * 16 + lr, cc = kk * 4 + lg;
        a[m] = *(const short8*)(lA + row * 64 + ((cc ^ (row & 7)) << 3));
      }
#pragma unroll
      for (int n = 0; n < 4; ++n) {
        int row = wc + n * 16 + lr, cc = kk * 4 + lg;
        b[n] = *(const short8*)(lB + row * 64 + ((cc ^ (row & 7)) << 3));
      }
      __builtin_amdgcn_s_setprio(1);
#pragma unroll
      for (int m = 0; m < 4; ++m)
#pragma unroll
        for (int n = 0; n < 4; ++n)
          acc[m][n] = mfma_bf16(a[m], b[n], acc[m][n]);
      __builtin_amdgcn_s_setprio(0);
    }
    __syncthreads();
  }

#pragma unroll
  for (int m = 0; m < 4; ++m)
#pragma unroll
    for (int n = 0; n < 4; ++n)
#pragma unroll
      for (int r = 0; r < 4; ++r) {
        int i = m0 + wr + m * 16 + lg * 4 + r;
        int j = n0 + wc + n * 16 + lr;
        float v = acc[m][n][r];
        if (MODE == 0) {
          int mat = j >> 10, rem = j & 1023;
          int h = rem >> 6, d = rem & 63;
          int b = i >> 12, s = i & 4095;
          int bh = b * HEADS + h;
          // fold 1/sqrt(64) * log2(e) into Q (softmax runs in exp2 domain)
          ushort_t val = f2b(mat == 0 ? v * 0.18033688f : v);
          if (mat == 0)      qg[((size_t)bh * SEQ + s) * DHEAD + d] = val;
          else if (mat == 1) kg[((size_t)bh * SEQ + s) * DHEAD + d] = val;
          else               vTg[((size_t)bh * DHEAD + d) * SEQ + s] = val;
        } else {
          outf[(size_t)i * N + j] = v;
        }
      }
}

// ---------------- paired-tile flash attention, 32x32 MFMA + in-register P ----------------
// Wave = one 32-row q-tile (4 waves = 128 q-rows). S^T = mfma32(K,Q): lane holds
// q-col = lane&31. P->bf16 via cvt_pk + permlane32_swap (NO LDS P). QK^T+softmax
// run per q-state; PV runs JOINTLY for both states: each V fragment is read once
// and feeds 4 independent o-chains (A0,A1,B0,B1) -> MFMA pipe stays fed.
// K/V double-buffered, prefetch-before-compute, 1 barrier/iter. LDS 64KB -> 2/CU.
struct QS {
  short8 qf[4];
  f32x16 o[2];
  float mrow, lsum;
};

__device__ __forceinline__ void attn_qk_sm(int diag, int w, int l31, int hi, int lane,
                                           const ushort_t* lKc, QS& st, short8 (&pa)[8]) {
  f32x16 s[4];
#pragma unroll
  for (int t = 0; t < 4; ++t)
#pragma unroll
    for (int r = 0; r < 16; ++r) s[t][r] = 0.f;

  // S^T = K Q^T : tile t covers k = t*32..+31; contraction over d (4 x K=16)
#pragma unroll
  for (int t = 0; t < 4; ++t) {
    int row = t * 32 + l31;
#pragma unroll
    for (int kb = 0; kb < 4; ++kb) {
      int cc = kb * 2 + hi;
      short8 kf = *(const short8*)(lKc + row * 64 + ((cc ^ (row & 7)) << 3));
      __builtin_amdgcn_s_setprio(1);
      s[t] = mfma32_bf16(kf, st.qf[kb], s[t]);
      __builtin_amdgcn_s_setprio(0);
    }
  }

  if (diag) {  // causal mask, local indices (q0 == j0)
    int q = w * 32 + l31;
#pragma unroll
    for (int t = 0; t < 4; ++t)
#pragma unroll
      for (int r = 0; r < 16; ++r)
        if (t * 32 + (r & 3) + 8 * (r >> 2) + 4 * hi > q) s[t][r] = -1e30f;
  }

  // online softmax (exp2 domain); max via v_max3 tree, xor32 completes the row
  float mx = fmaxf(s[0][0], s[0][1]);
#pragma unroll
  for (int t = 0; t < 4; ++t)
#pragma unroll
    for (int r = (t == 0 ? 2 : 0); r < 16; r += 2)
      mx = max3f(mx, s[t][r], s[t][r + 1]);
  mx = fmaxf(mx, __shfl_xor(mx, 32));
  float mo = st.mrow;
  if (!__all(mx - mo <= 8.0f)) {  // defer-max THR=8
    float mn = fmaxf(mo, mx);
    float al = exp2_fast(mo - mn);
    st.mrow = mn;
    st.lsum *= al;
#pragma unroll
    for (int r = 0; r < 16; ++r) {
      float alo = __shfl(al, (r & 3) + 8 * (r >> 2) + 4 * hi);
      st.o[0][r] *= alo;
      st.o[1][r] *= alo;
    }
  }
  float mloc = st.mrow;
  float rs = 0.f;
#pragma unroll
  for (int t = 0; t < 4; ++t)
#pragma unroll
    for (int r = 0; r < 16; ++r) {
      float p = exp2_fast(s[t][r] - mloc);
      s[t][r] = p;
      rs += p;
    }
  rs += __shfl_xor(rs, 32);
  st.lsum += rs;

  // pack P -> bf16 A-fragments in registers (cvt_pk + permlane32_swap)
#pragma unroll
  for (int t = 0; t < 4; ++t) {
    uint_t w0 = cvt_pk_bf16(s[t][0], s[t][1]);
    uint_t w1 = cvt_pk_bf16(s[t][2], s[t][3]);
    uint_t w2 = cvt_pk_bf16(s[t][4], s[t][5]);
    uint_t w3 = cvt_pk_bf16(s[t][6], s[t][7]);
    permlane_swap(w0, w2);
    permlane_swap(w1, w3);
    u32x4 f0 = {w0, w1, w2, w3};
    pa[2 * t] = __builtin_bit_cast(short8, f0);
    uint_t w4 = cvt_pk_bf16(s[t][8], s[t][9]);
    uint_t w5 = cvt_pk_bf16(s[t][10], s[t][11]);
    uint_t w6 = cvt_pk_bf16(s[t][12], s[t][13]);
    uint_t w7 = cvt_pk_bf16(s[t][14], s[t][15]);
    permlane_swap(w4, w6);
    permlane_swap(w5, w7);
    u32x4 f1 = {w4, w5, w6, w7};
    pa[2 * t + 1] = __builtin_bit_cast(short8, f1);
  }
}

// joint PV: V fragment read once, feeds up to 4 independent accumulation chains
__device__ __forceinline__ void attn_pv(const ushort_t* lVc, int l31, int hi,
                                        const short8 (&paA)[8], const short8 (&paB)[8],
                                        QS& stA, QS& stB, bool doB) {
  int row0 = l31, row1 = 32 + l31;
#pragma unroll
  for (int kb = 0; kb < 8; ++kb) {
    int cc = kb * 2 + hi;
    short8 vf0 = *(const short8*)(lVc + row0 * 128 + ((cc ^ (row0 & 15)) << 3));
    short8 vf1 = *(const short8*)(lVc + row1 * 128 + ((cc ^ (row1 & 15)) << 3));
    __builtin_amdgcn_s_setprio(1);
    stA.o[0] = mfma32_bf16(paA[kb], vf0, stA.o[0]);
    stA.o[1] = mfma32_bf16(paA[kb], vf1, stA.o[1]);
    if (doB) {
      stB.o[0] = mfma32_bf16(paB[kb], vf0, stB.o[0]);
      stB.o[1] = mfma32_bf16(paB[kb], vf1, stB.o[1]);
    }
    __builtin_amdgcn_s_setprio(0);
  }
}

__device__ __forceinline__ void attn_epilogue(const QS& st, int q0, int bh,
                                              int w, int l31, int hi,
                                              ushort_t* __restrict__ og) {
  int b = bh >> 4, h = bh & 15;
#pragma unroll
  for (int r = 0; r < 16; ++r) {
    int qr = (r & 3) + 8 * (r >> 2) + 4 * hi;
    float ls = __shfl(st.lsum, qr);
    float inv = 1.0f / ls;
    int srow = q0 + w * 32 + qr;
#pragma unroll
    for (int nd = 0; nd < 2; ++nd) {
      int col = h * 64 + nd * 32 + l31;
      og[((size_t)b * SEQ + srow) * HID + col] = f2b(st.o[nd][r] * inv);
    }
  }
}

__global__ __launch_bounds__(256, 2)
void attn_kernel(const ushort_t* __restrict__ qg, const ushort_t* __restrict__ kg,
                 const ushort_t* __restrict__ vTg, ushort_t* __restrict__ og) {
  __shared__ ushort_t lK[2][128 * 64];
  __shared__ ushort_t lV[2][64 * 128];

  int bid = blockIdx.x;
  int wg = (bid & 7) * 64 + (bid >> 3);  // XCD-chunked: 4 bh per XCD
  int bh = wg >> 4;
  int pair = wg & 15;
  int qtA = 31 - pair, qtB = pair;       // qtA >= 16 > qtB
  int q0A = qtA * 128, q0B = qtB * 128;
  const ushort_t* Q = qg + (size_t)bh * SEQ * DHEAD;
  const ushort_t* Kp = kg + (size_t)bh * SEQ * DHEAD;
  const ushort_t* Vt = vTg + (size_t)bh * DHEAD * SEQ;

  int tid = threadIdx.x, lane = tid & 63, w = tid >> 6;
  int l31 = lane & 31, hi = lane >> 5;

  // prologue: stage QA->lK[1], QB->lV[1], K0->lK[0], V0->lV[0] in one burst
#pragma unroll
  for (int i = 0; i < 4; ++i) {
    int c = i * 256 + tid;
    int row = c >> 3, cc = c & 7;
    size_t qoff = (cc ^ (row & 7)) * 8;
    gload16(Q + (size_t)(q0A + row) * DHEAD + qoff, &lK[1][c * 8]);
    gload16(Q + (size_t)(q0B + row) * DHEAD + qoff, &lV[1][c * 8]);
    gload16(Kp + (size_t)row * DHEAD + qoff, &lK[0][c * 8]);
  }
#pragma unroll
  for (int i = 0; i < 4; ++i) {
    int c = i * 256 + tid;
    int d = c >> 4, cc = c & 15;
    gload16(Vt + (size_t)d * SEQ + (cc ^ (d & 15)) * 8, &lV[0][c * 8]);
  }
  __syncthreads();

  QS stA, stB;
  int qrow = w * 32 + l31;
#pragma unroll
  for (int kb = 0; kb < 4; ++kb) {
    int cc = kb * 2 + hi;
    int off = qrow * 64 + ((cc ^ (qrow & 7)) << 3);
    stA.qf[kb] = *(const short8*)(&lK[1][0] + off);
    stB.qf[kb] = *(const short8*)(&lV[1][0] + off);
  }
  asm volatile("s_waitcnt lgkmcnt(0)");
  __syncthreads();  // all waves have Q in regs before buf1 is overwritten

  stA.mrow = -1e30f; stA.lsum = 0.f;
  stB.mrow = -1e30f; stB.lsum = 0.f;
#pragma unroll
  for (int nd = 0; nd < 2; ++nd)
#pragma unroll
    for (int r = 0; r < 16; ++r) { stA.o[nd][r] = 0.f; stB.o[nd][r] = 0.f; }

  for (int jt = 0; jt <= qtA; ++jt) {
    int cur = jt & 1, nxt = cur ^ 1;
    // prefetch next K/V tile BEFORE computing current (latency hides under MFMA)
    if (jt < qtA) {
      int j0n = (jt + 1) * 128;
#pragma unroll
      for (int i = 0; i < 4; ++i) {
        int c = i * 256 + tid;
        int row = c >> 3, cc = c & 7;
        gload16(Kp + (size_t)(j0n + row) * DHEAD + (cc ^ (row & 7)) * 8, &lK[nxt][c * 8]);
      }
#pragma unroll
      for (int i = 0; i < 4; ++i) {
        int c = i * 256 + tid;
        int d = c >> 4, cc = c & 15;
        gload16(Vt + (size_t)d * SEQ + j0n + (cc ^ (d & 15)) * 8, &lV[nxt][c * 8]);
      }
    }

    bool doB = (jt <= qtB);
    short8 paA[8], paB[8];
    attn_qk_sm(jt == qtA, w, l31, hi, lane, &lK[cur][0], stA, paA);
    if (doB) attn_qk_sm(jt == qtB, w, l31, hi, lane, &lK[cur][0], stB, paB);
    attn_pv(&lV[cur][0], l31, hi, paA, paB, stA, stB, doB);

    __syncthreads();  // drains prefetch vmcnt; next buffer ready, cur reusable
  }

  attn_epilogue(stA, q0A, bh, w, l31, hi, og);
  attn_epilogue(stB, q0B, bh, w, l31, hi, og);
}

extern "C" void kernel_launch(void* const* d_in, const int* in_sizes, int n_in,
                              void* d_out, int out_size, void* d_ws, size_t ws_size,
                              hipStream_t stream) {
  const float* x = (const float*)d_in[0];
  const float* wqkv = (const float*)d_in[1];
  const float* wout = (const float*)d_in[2];
  float* out = (float*)d_out;

  if (ws_size < 75497472u) return;  // need 75.5 MB scratch

  char* ws = (char*)d_ws;
  ushort_t* xb    = (ushort_t*)(ws);               // 8192x1024 bf16 (reused as attn out)
  ushort_t* wqkvT = (ushort_t*)(ws + 16777216);    // 3072x1024
  ushort_t* woutT = (ushort_t*)(ws + 23068672);    // 1024x1024
  ushort_t* qgb   = (ushort_t*)(ws + 25165824);    // [32][4096][64]
  ushort_t* kgb   = (ushort_t*)(ws + 41943040);    // [32][4096][64]
  ushort_t* vTb   = (ushort_t*)(ws + 58720256);    // [32][64][4096]
  ushort_t* ob    = xb;

  cvt_kernel<<<dim3(8192), dim3(256), 0, stream>>>(x, xb, 2097152);
  transpose_cvt_kernel<<<dim3(96, 32), dim3(256), 0, stream>>>(wqkv, wqkvT, 1024, 3072);
  transpose_cvt_kernel<<<dim3(32, 32), dim3(256), 0, stream>>>(wout, woutT, 1024, 1024);
  gemm_kernel<0><<<dim3(64, 24), dim3(256), 0, stream>>>(xb, wqkvT, 8192, 3072, 1024,
                                                         qgb, kgb, vTb, nullptr);
  attn_kernel<<<dim3(512), dim3(256), 0, stream>>>(qgb, kgb, vTb, ob);
  gemm_kernel<1><<<dim3(64, 8), dim3(256), 0, stream>>>(ob, woutT, 8192, 1024, 1024,
                                                        nullptr, nullptr, nullptr, out);
}

// Round 10
// 217.599 us; speedup vs baseline: 1.1723x; 1.1723x over previous
//
#include <hip/hip_runtime.h>
#include <hip/hip_bf16.h>

#define SEQ 4096
#define BATCH 2
#define HEADS 16
#define DHEAD 64
#define HID 1024

typedef unsigned short ushort_t;
typedef unsigned int uint_t;
typedef __attribute__((ext_vector_type(8))) short short8;
typedef __attribute__((ext_vector_type(4))) float f32x4;
typedef __attribute__((ext_vector_type(16))) float f32x16;
typedef __attribute__((ext_vector_type(4))) uint_t u32x4;

__device__ __forceinline__ float exp2_fast(float x) {
  return __builtin_amdgcn_exp2f(x);  // v_exp_f32 computes 2^x natively
}

__device__ __forceinline__ float max3f(float a, float b, float c) {
  float r;
  asm("v_max3_f32 %0, %1, %2, %3" : "=v"(r) : "v"(a), "v"(b), "v"(c));
  return r;
}

__device__ __forceinline__ ushort_t f2b(float f) {
  unsigned u = __builtin_bit_cast(unsigned, f);
  unsigned r = 0x7fffu + ((u >> 16) & 1u);
  return (ushort_t)((u + r) >> 16);
}

__device__ __forceinline__ uint_t cvt_pk_bf16(float lo, float hi) {
  uint_t r;
  asm("v_cvt_pk_bf16_f32 %0, %1, %2" : "=v"(r) : "v"(lo), "v"(hi));
  return r;
}

// swap a's hi-32-lane half with b's lo-32-lane half (CDNA4 cross-lane, VALU pipe)
__device__ __forceinline__ void permlane_swap(uint_t& a, uint_t& b) {
  asm("v_permlane32_swap_b32 %0, %1" : "+v"(a), "+v"(b));
}

__device__ __forceinline__ void gload16(const void* g, void* l) {
  __builtin_amdgcn_global_load_lds((const __attribute__((address_space(1))) void*)g,
                                   (__attribute__((address_space(3))) void*)l, 16, 0, 0);
}

__device__ __forceinline__ f32x4 mfma_bf16(short8 a, short8 b, f32x4 c) {
  return __builtin_amdgcn_mfma_f32_16x16x32_bf16(a, b, c, 0, 0, 0);
}

__device__ __forceinline__ f32x16 mfma32_bf16(short8 a, short8 b, f32x16 c) {
  return __builtin_amdgcn_mfma_f32_32x32x16_bf16(a, b, c, 0, 0, 0);
}

// ---------------- fp32 -> bf16 elementwise (vectorized) ----------------
__global__ void cvt_kernel(const float* __restrict__ in, ushort_t* __restrict__ out, int n4) {
  int i = blockIdx.x * blockDim.x + threadIdx.x;
  if (i >= n4) return;
  float4 v = reinterpret_cast<const float4*>(in)[i];
  ushort4 o;
  o.x = f2b(v.x); o.y = f2b(v.y); o.z = f2b(v.z); o.w = f2b(v.w);
  reinterpret_cast<ushort4*>(out)[i] = o;
}

// ---------------- transpose + convert: in[rows][cols] f32 -> out[cols][rows] bf16 ----------------
__global__ void transpose_cvt_kernel(const float* __restrict__ in, ushort_t* __restrict__ out,
                                     int rows, int cols) {
  __shared__ float tile[32][33];
  int tx = threadIdx.x & 31, ty = threadIdx.x >> 5;
  int r0 = blockIdx.y * 32, c0 = blockIdx.x * 32;
#pragma unroll
  for (int i = 0; i < 32; i += 8)
    tile[ty + i][tx] = in[(size_t)(r0 + ty + i) * cols + c0 + tx];
  __syncthreads();
#pragma unroll
  for (int i = 0; i < 32; i += 8)
    out[(size_t)(c0 + ty + i) * rows + r0 + tx] = f2b(tile[tx][ty + i]);
}

// ---------------- bf16 GEMM: C = A[M][K] * BT[N][K]^T ----------------
// MODE 0: scatter-write q(*0.125*log2e)/k/vT bf16.  MODE 1: write fp32 C.
template <int MODE>
__global__ __launch_bounds__(256, 2)
void gemm_kernel(const ushort_t* __restrict__ A, const ushort_t* __restrict__ BT,
                 int M, int N, int K,
                 ushort_t* __restrict__ qg, ushort_t* __restrict__ kg,
                 ushort_t* __restrict__ vTg, float* __restrict__ outf) {
  __shared__ ushort_t lA[128 * 64];
  __shared__ ushort_t lB[128 * 64];
  int tid = threadIdx.x;
  int lane = tid & 63, w = tid >> 6;
  int m0 = blockIdx.x * 128, n0 = blockIdx.y * 128;
  int wr = (w >> 1) * 64, wc = (w & 1) * 64;
  int lr = lane & 15, lg = lane >> 4;

  const f32x4 z4 = {0.f, 0.f, 0.f, 0.f};
  f32x4 acc[4][4];
#pragma unroll
  for (int m = 0; m < 4; ++m)
#pragma unroll
    for (int n = 0; n < 4; ++n) acc[m][n] = z4;

  int ktiles = K >> 6;
  for (int kt = 0; kt < ktiles; ++kt) {
    int k0 = kt << 6;
#pragma unroll
    for (int i = 0; i < 4; ++i) {
      int c = i * 256 + tid;
      int row = c >> 3, cc = c & 7;
      gload16(A + (size_t)(m0 + row) * K + k0 + (cc ^ (row & 7)) * 8, lA + c * 8);
    }
#pragma unroll
    for (int i = 0; i < 4; ++i) {
      int c = i * 256 + tid;
      int row = c >> 3, cc = c & 7;
      gload16(BT + (size_t)(n0 + row) * K + k0 + (cc ^ (row & 7)) * 8, lB + c * 8);
    }
    __syncthreads();
#pragma unroll
    for (int kk = 0; kk < 2; ++kk) {
      short8 a[4], b[4];
#pragma unroll
      for (int m = 0; m < 4; ++m) {
        int row = wr + m * 16 + lr, cc = kk * 4 + lg;
        a[m] = *(const short8*)(lA + row * 64 + ((cc ^ (row & 7)) << 3));
      }
#pragma unroll
      for (int n = 0; n < 4; ++n) {
        int row = wc + n * 16 + lr, cc = kk * 4 + lg;
        b[n] = *(const short8*)(lB + row * 64 + ((cc ^ (row & 7)) << 3));
      }
      __builtin_amdgcn_s_setprio(1);
#pragma unroll
      for (int m = 0; m < 4; ++m)
#pragma unroll
        for (int n = 0; n < 4; ++n)
          acc[m][n] = mfma_bf16(a[m], b[n], acc[m][n]);
      __builtin_amdgcn_s_setprio(0);
    }
    __syncthreads();
  }

#pragma unroll
  for (int m = 0; m < 4; ++m)
#pragma unroll
    for (int n = 0; n < 4; ++n)
#pragma unroll
      for (int r = 0; r < 4; ++r) {
        int i = m0 + wr + m * 16 + lg * 4 + r;
        int j = n0 + wc + n * 16 + lr;
        float v = acc[m][n][r];
        if (MODE == 0) {
          int mat = j >> 10, rem = j & 1023;
          int h = rem >> 6, d = rem & 63;
          int b = i >> 12, s = i & 4095;
          int bh = b * HEADS + h;
          // fold 1/sqrt(64) * log2(e) into Q (softmax runs in exp2 domain)
          ushort_t val = f2b(mat == 0 ? v * 0.18033688f : v);
          if (mat == 0)      qg[((size_t)bh * SEQ + s) * DHEAD + d] = val;
          else if (mat == 1) kg[((size_t)bh * SEQ + s) * DHEAD + d] = val;
          else               vTg[((size_t)bh * DHEAD + d) * SEQ + s] = val;
        } else {
          outf[(size_t)i * N + j] = v;
        }
      }
}

// ---------------- paired-tile flash attention, 32x32 MFMA + in-register P ----------------
// R8 structure (proven 115us): per-state QK+softmax+PV sequential (register-
// feasible); P never touches LDS (cvt_pk + permlane32_swap). R10 adds only
// zero-lifetime softmax micro-opts: v_max3 tree + 4-chain parallel sum.
// K/V double-buffered, prefetch-before-compute, 1 barrier/iter. LDS 64KB -> 2/CU.
struct QS {
  short8 qf[4];
  f32x16 o[2];
  float mrow, lsum;
};

__device__ __forceinline__ void attn_tile(int diag, int w, int l31, int hi, int lane,
                                          const ushort_t* lKc, const ushort_t* lVc, QS& st) {
  f32x16 s[4];
#pragma unroll
  for (int t = 0; t < 4; ++t)
#pragma unroll
    for (int r = 0; r < 16; ++r) s[t][r] = 0.f;

  // S^T = K Q^T : tile t covers k = t*32..+31; contraction over d (4 x K=16)
#pragma unroll
  for (int t = 0; t < 4; ++t) {
    int row = t * 32 + l31;
#pragma unroll
    for (int kb = 0; kb < 4; ++kb) {
      int cc = kb * 2 + hi;
      short8 kf = *(const short8*)(lKc + row * 64 + ((cc ^ (row & 7)) << 3));
      __builtin_amdgcn_s_setprio(1);
      s[t] = mfma32_bf16(kf, st.qf[kb], s[t]);
      __builtin_amdgcn_s_setprio(0);
    }
  }

  if (diag) {  // causal mask, local indices (q0 == j0)
    int q = w * 32 + l31;
#pragma unroll
    for (int t = 0; t < 4; ++t)
#pragma unroll
      for (int r = 0; r < 16; ++r)
        if (t * 32 + (r & 3) + 8 * (r >> 2) + 4 * hi > q) s[t][r] = -1e30f;
  }

  // online softmax (exp2 domain); v_max3 tree, xor32 completes the row
  float mx = fmaxf(s[0][0], s[0][1]);
#pragma unroll
  for (int t = 0; t < 4; ++t)
#pragma unroll
    for (int r = (t == 0 ? 2 : 0); r < 16; r += 2)
      mx = max3f(mx, s[t][r], s[t][r + 1]);
  mx = fmaxf(mx, __shfl_xor(mx, 32));
  float mo = st.mrow;
  if (!__all(mx - mo <= 8.0f)) {  // defer-max THR=8
    float mn = fmaxf(mo, mx);
    float al = exp2_fast(mo - mn);
    st.mrow = mn;
    st.lsum *= al;
#pragma unroll
    for (int r = 0; r < 16; ++r) {
      float alo = __shfl(al, (r & 3) + 8 * (r >> 2) + 4 * hi);
      st.o[0][r] *= alo;
      st.o[1][r] *= alo;
    }
  }
  float mloc = st.mrow;
  // exp + sum: 4 parallel accumulation chains (explicit reassociation) to cut
  // the 64-long serial add dependency ~4x
  float rsv[4];
#pragma unroll
  for (int t = 0; t < 4; ++t) {
    float a = 0.f;
#pragma unroll
    for (int r = 0; r < 16; ++r) {
      float p = exp2_fast(s[t][r] - mloc);
      s[t][r] = p;
      a += p;
    }
    rsv[t] = a;
  }
  float rs = (rsv[0] + rsv[1]) + (rsv[2] + rsv[3]);
  rs += __shfl_xor(rs, 32);
  st.lsum += rs;

  // pack P -> bf16 A-fragments in registers (cvt_pk + permlane32_swap)
  short8 pa[8];
#pragma unroll
  for (int t = 0; t < 4; ++t) {
    uint_t w0 = cvt_pk_bf16(s[t][0], s[t][1]);
    uint_t w1 = cvt_pk_bf16(s[t][2], s[t][3]);
    uint_t w2 = cvt_pk_bf16(s[t][4], s[t][5]);
    uint_t w3 = cvt_pk_bf16(s[t][6], s[t][7]);
    permlane_swap(w0, w2);
    permlane_swap(w1, w3);
    u32x4 f0 = {w0, w1, w2, w3};
    pa[2 * t] = __builtin_bit_cast(short8, f0);
    uint_t w4 = cvt_pk_bf16(s[t][8], s[t][9]);
    uint_t w5 = cvt_pk_bf16(s[t][10], s[t][11]);
    uint_t w6 = cvt_pk_bf16(s[t][12], s[t][13]);
    uint_t w7 = cvt_pk_bf16(s[t][14], s[t][15]);
    permlane_swap(w4, w6);
    permlane_swap(w5, w7);
    u32x4 f1 = {w4, w5, w6, w7};
    pa[2 * t + 1] = __builtin_bit_cast(short8, f1);
  }

  // O += P V : B = V^T rows d (from lV), A = pa (registers)
#pragma unroll
  for (int nd = 0; nd < 2; ++nd) {
    int row = nd * 32 + l31;
#pragma unroll
    for (int kb = 0; kb < 8; ++kb) {
      int cc = kb * 2 + hi;
      short8 vf = *(const short8*)(lVc + row * 128 + ((cc ^ (row & 15)) << 3));
      __builtin_amdgcn_s_setprio(1);
      st.o[nd] = mfma32_bf16(pa[kb], vf, st.o[nd]);
      __builtin_amdgcn_s_setprio(0);
    }
  }
}

__device__ __forceinline__ void attn_epilogue(const QS& st, int q0, int bh,
                                              int w, int l31, int hi,
                                              ushort_t* __restrict__ og) {
  int b = bh >> 4, h = bh & 15;
#pragma unroll
  for (int r = 0; r < 16; ++r) {
    int qr = (r & 3) + 8 * (r >> 2) + 4 * hi;
    float ls = __shfl(st.lsum, qr);
    float inv = 1.0f / ls;
    int srow = q0 + w * 32 + qr;
#pragma unroll
    for (int nd = 0; nd < 2; ++nd) {
      int col = h * 64 + nd * 32 + l31;
      og[((size_t)b * SEQ + srow) * HID + col] = f2b(st.o[nd][r] * inv);
    }
  }
}

__global__ __launch_bounds__(256, 2)
void attn_kernel(const ushort_t* __restrict__ qg, const ushort_t* __restrict__ kg,
                 const ushort_t* __restrict__ vTg, ushort_t* __restrict__ og) {
  __shared__ ushort_t lK[2][128 * 64];
  __shared__ ushort_t lV[2][64 * 128];

  int bid = blockIdx.x;
  int wg = (bid & 7) * 64 + (bid >> 3);  // XCD-chunked: 4 bh per XCD
  int bh = wg >> 4;
  int pair = wg & 15;
  int qtA = 31 - pair, qtB = pair;       // qtA >= 16 > qtB
  int q0A = qtA * 128, q0B = qtB * 128;
  const ushort_t* Q = qg + (size_t)bh * SEQ * DHEAD;
  const ushort_t* Kp = kg + (size_t)bh * SEQ * DHEAD;
  const ushort_t* Vt = vTg + (size_t)bh * DHEAD * SEQ;

  int tid = threadIdx.x, lane = tid & 63, w = tid >> 6;
  int l31 = lane & 31, hi = lane >> 5;

  // prologue: stage QA->lK[1], QB->lV[1], K0->lK[0], V0->lV[0] in one burst
#pragma unroll
  for (int i = 0; i < 4; ++i) {
    int c = i * 256 + tid;
    int row = c >> 3, cc = c & 7;
    size_t qoff = (cc ^ (row & 7)) * 8;
    gload16(Q + (size_t)(q0A + row) * DHEAD + qoff, &lK[1][c * 8]);
    gload16(Q + (size_t)(q0B + row) * DHEAD + qoff, &lV[1][c * 8]);
    gload16(Kp + (size_t)row * DHEAD + qoff, &lK[0][c * 8]);
  }
#pragma unroll
  for (int i = 0; i < 4; ++i) {
    int c = i * 256 + tid;
    int d = c >> 4, cc = c & 15;
    gload16(Vt + (size_t)d * SEQ + (cc ^ (d & 15)) * 8, &lV[0][c * 8]);
  }
  __syncthreads();

  QS stA, stB;
  int qrow = w * 32 + l31;
#pragma unroll
  for (int kb = 0; kb < 4; ++kb) {
    int cc = kb * 2 + hi;
    int off = qrow * 64 + ((cc ^ (qrow & 7)) << 3);
    stA.qf[kb] = *(const short8*)(&lK[1][0] + off);
    stB.qf[kb] = *(const short8*)(&lV[1][0] + off);
  }
  asm volatile("s_waitcnt lgkmcnt(0)");
  __syncthreads();  // all waves have Q in regs before buf1 is overwritten

  stA.mrow = -1e30f; stA.lsum = 0.f;
  stB.mrow = -1e30f; stB.lsum = 0.f;
#pragma unroll
  for (int nd = 0; nd < 2; ++nd)
#pragma unroll
    for (int r = 0; r < 16; ++r) { stA.o[nd][r] = 0.f; stB.o[nd][r] = 0.f; }

  for (int jt = 0; jt <= qtA; ++jt) {
    int cur = jt & 1, nxt = cur ^ 1;
    // prefetch next K/V tile BEFORE computing current (latency hides under MFMA)
    if (jt < qtA) {
      int j0n = (jt + 1) * 128;
#pragma unroll
      for (int i = 0; i < 4; ++i) {
        int c = i * 256 + tid;
        int row = c >> 3, cc = c & 7;
        gload16(Kp + (size_t)(j0n + row) * DHEAD + (cc ^ (row & 7)) * 8, &lK[nxt][c * 8]);
      }
#pragma unroll
      for (int i = 0; i < 4; ++i) {
        int c = i * 256 + tid;
        int d = c >> 4, cc = c & 15;
        gload16(Vt + (size_t)d * SEQ + j0n + (cc ^ (d & 15)) * 8, &lV[nxt][c * 8]);
      }
    }

    attn_tile(jt == qtA, w, l31, hi, lane, &lK[cur][0], &lV[cur][0], stA);
    if (jt <= qtB)
      attn_tile(jt == qtB, w, l31, hi, lane, &lK[cur][0], &lV[cur][0], stB);

    __syncthreads();  // drains prefetch vmcnt; next buffer ready, cur reusable
  }

  attn_epilogue(stA, q0A, bh, w, l31, hi, og);
  attn_epilogue(stB, q0B, bh, w, l31, hi, og);
}

extern "C" void kernel_launch(void* const* d_in, const int* in_sizes, int n_in,
                              void* d_out, int out_size, void* d_ws, size_t ws_size,
                              hipStream_t stream) {
  const float* x = (const float*)d_in[0];
  const float* wqkv = (const float*)d_in[1];
  const float* wout = (const float*)d_in[2];
  float* out = (float*)d_out;

  if (ws_size < 75497472u) return;  // need 75.5 MB scratch

  char* ws = (char*)d_ws;
  ushort_t* xb    = (ushort_t*)(ws);               // 8192x1024 bf16 (reused as attn out)
  ushort_t* wqkvT = (ushort_t*)(ws + 16777216);    // 3072x1024
  ushort_t* woutT = (ushort_t*)(ws + 23068672);    // 1024x1024
  ushort_t* qgb   = (ushort_t*)(ws + 25165824);    // [32][4096][64]
  ushort_t* kgb   = (ushort_t*)(ws + 41943040);    // [32][4096][64]
  ushort_t* vTb   = (ushort_t*)(ws + 58720256);    // [32][64][4096]
  ushort_t* ob    = xb;

  cvt_kernel<<<dim3(8192), dim3(256), 0, stream>>>(x, xb, 2097152);
  transpose_cvt_kernel<<<dim3(96, 32), dim3(256), 0, stream>>>(wqkv, wqkvT, 1024, 3072);
  transpose_cvt_kernel<<<dim3(32, 32), dim3(256), 0, stream>>>(wout, woutT, 1024, 1024);
  gemm_kernel<0><<<dim3(64, 24), dim3(256), 0, stream>>>(xb, wqkvT, 8192, 3072, 1024,
                                                         qgb, kgb, vTb, nullptr);
  attn_kernel<<<dim3(512), dim3(256), 0, stream>>>(qgb, kgb, vTb, ob);
  gemm_kernel<1><<<dim3(64, 8), dim3(256), 0, stream>>>(ob, woutT, 8192, 1024, 1024,
                                                        nullptr, nullptr, nullptr, out);
}